// Round 2
// baseline (81.621 us; speedup 1.0000x reference)
//
#include <hip/hip_runtime.h>
#include <cfloat>
#include <cmath>

// Problem constants (from reference)
#define Nn 32
#define Qq 300
#define Cc 92
#define Tt 32
#define KCOLS 5     // ceil(300/64) columns owned per lane (Dijkstra fallback)
#define GSZ 10      // threads per row-group in the auction scan
#define GCOLS 30    // contiguous cols per scan thread (10*30 = 300)
#define AUCTION_ROUNDS 10
#define AUCTION_EPS 1e-3f

#define SLICES 8            // query slices per batch in cost_kernel
#define RPS 38              // rows (queries) per slice: 8*38 = 304 >= 300
#define CTHREADS 256
#define ATHREADS 320        // 5 waves: scan needs 320, leaders 32
#define FTHREADS 256        // 4 waves stage diag; wave 0 runs Dijkstra

// Workspace layout (floats). Fully rewritten every launch (ws gets poisoned).
#define DIAG_OFF   0                        // [N][T][Q]  = 307200 f
#define MXIS_OFF   (Nn * Tt * Qq)           // [N][Q] float2 = 19200 f
#define STATE_OFF  (MXIS_OFF + 2 * Nn * Qq) // per-batch 640 f
#define STATE_STRIDE 640                    // v[300] | u[0..32] @300 | colrow int[300] @334 | mask @634

// ---------------------------------------------------------------------------
// DPP full-wave (64-lane) float min, broadcast to all lanes (~6 dep. v_min).
// Used only in the Dijkstra fallback.
// ---------------------------------------------------------------------------
__device__ inline float wave_min_bcast(float x) {
#define DPPMIN(ctrl) { int _t = __builtin_amdgcn_update_dpp( \
        __float_as_int(x), __float_as_int(x), ctrl, 0xf, 0xf, false); \
        x = fminf(x, __int_as_float(_t)); }
    DPPMIN(0x111) DPPMIN(0x112) DPPMIN(0x114) DPPMIN(0x118)
    DPPMIN(0x142) DPPMIN(0x143)
#undef DPPMIN
    return __int_as_float(__builtin_amdgcn_readlane(__float_as_int(x), 63));
}

// Select a[k] for runtime k (cndmask chain, no scratch).
__device__ inline int sel5i(const int a[KCOLS], int k) {
    int r = a[0];
    if (k == 1) r = a[1];
    if (k == 2) r = a[2];
    if (k == 3) r = a[3];
    if (k == 4) r = a[4];
    return r;
}

__device__ inline float readlane_f(float v, int lane) {
    return __int_as_float(__builtin_amdgcn_readlane(__float_as_int(v), lane));
}

// cost = 5*L1 + cls - 2*giou   (cls = -softmax_prob[label], passed in).
// Operation order identical to the previous session's det_cost so every cost
// bit matches the verified baseline.
__device__ inline float det_cost_real(float cx, float cy, float w, float h,
                                      float bcx, float bcy, float bw, float bh,
                                      float cls) {
    const float ax0 = cx - 0.5f * w, ay0 = cy - 0.5f * h;
    const float ax1 = cx + 0.5f * w, ay1 = cy + 0.5f * h;
    const float areaA = (ax1 - ax0) * (ay1 - ay0);

    const float l1 = fabsf(cx - bcx) + fabsf(cy - bcy) +
                     fabsf(w - bw) + fabsf(h - bh);

    const float bx0 = bcx - 0.5f * bw, by0 = bcy - 0.5f * bh;
    const float bx1 = bcx + 0.5f * bw, by1 = bcy + 0.5f * bh;
    const float areaB = (bx1 - bx0) * (by1 - by0);

    const float ltx = fmaxf(ax0, bx0), lty = fmaxf(ay0, by0);
    const float rbx = fminf(ax1, bx1), rby = fminf(ay1, by1);
    const float iw = fmaxf(rbx - ltx, 0.f), ih = fmaxf(rby - lty, 0.f);
    const float inter = iw * ih;
    const float uni = areaA + areaB - inter;
    const float iou = inter / uni;

    const float ex0 = fminf(ax0, bx0), ey0 = fminf(ay0, by0);
    const float ex1 = fmaxf(ax1, bx1), ey1 = fmaxf(ay1, by1);
    const float areaC = fmaxf(ex1 - ex0, 0.f) * fmaxf(ey1 - ey0, 0.f);
    const float giou = iou - (areaC - uni) / areaC;

    return 5.f * l1 + cls - 2.f * giou;
}

// ---------------------------------------------------------------------------
// Kernel 1: cost matrix + softmax stats at 256-block parallelism.
// Block (b, s) owns queries [s*38, s*38+38) of batch b. Softmax is computed
// 4-lanes-per-row with the exact same partial-accumulator decomposition as
// the previous fused kernel's softmax_lds (bit-identical mx / inv_s).
// ---------------------------------------------------------------------------
__global__ __launch_bounds__(CTHREADS) void cost_kernel(
    const float* __restrict__ logits,   // [N,Q,C]
    const float* __restrict__ pboxes,   // [N,Q,4]
    const int*   __restrict__ tlabels,  // [N*T]
    const float* __restrict__ tboxes,   // [N*T,4]
    float* __restrict__ ws)
{
    const int bs = blockIdx.x;
    const int b = bs >> 3, s = bs & 7;
    const int q0 = s * RPS;
    const int nq = min(RPS, Qq - q0);   // 38, except 34 for s==7

    __shared__ float2 s_mxis[RPS];
    __shared__ float  s_tb[Tt * 4];
    __shared__ int    s_tl[Tt];

    const int tid = threadIdx.x;
    if (tid < Tt * 4) s_tb[tid] = tboxes[b * Tt * 4 + tid];
    if (tid < Tt)     s_tl[tid] = tlabels[b * Tt + tid];

    // ---- softmax stats: 4 lanes per query row, bit-identical recombine ----
    const int r = tid >> 2, j = tid & 3;
    if (r < nq) {
        const float* row = logits + ((size_t)(b * Qq) + q0 + r) * Cc;
        float mj = -FLT_MAX;
#pragma unroll
        for (int c = 0; c < Cc; c += 4) mj = fmaxf(mj, row[c + j]);
        const float ma = fmaxf(mj, __shfl_xor(mj, 1, 4));
        const float mx = fmaxf(ma, __shfl_xor(ma, 2, 4));   // = max(max(m0,m1),max(m2,m3))
        float sj = 0.f;
#pragma unroll
        for (int c = 0; c < Cc; c += 4) sj += __expf(row[c + j] - mx);
        const float sa   = sj + __shfl_xor(sj, 1, 4);       // s0+s1 | s2+s3
        const float ssum = sa + __shfl_xor(sa, 2, 4);       // (s0+s1)+(s2+s3)
        if (j == 0) {
            const float2 mi = make_float2(mx, 1.f / ssum);
            s_mxis[r] = mi;
            reinterpret_cast<float2*>(ws + MXIS_OFF)[b * Qq + q0 + r] = mi;
        }
    }
    __syncthreads();

    // ---- diag cost entries for this slice: 32*nq entries across 256 thr ----
    float* diagb = ws + DIAG_OFF + (size_t)b * (Tt * Qq);
    for (int e = tid; e < Tt * RPS; e += CTHREADS) {
        const int t = e / RPS, lq = e - t * RPS;
        const int q = q0 + lq;
        if (q < Qq) {
            const float2 mi = s_mxis[lq];
            const float cls =
                -__expf(logits[((size_t)(b * Qq) + q) * Cc + s_tl[t]] - mi.x) * mi.y;
            const float4 pbv = reinterpret_cast<const float4*>(pboxes)[b * Qq + q];
            diagb[t * Qq + q] = det_cost_real(pbv.x, pbv.y, pbv.z, pbv.w,
                                              s_tb[t * 4 + 0], s_tb[t * 4 + 1],
                                              s_tb[t * 4 + 2], s_tb[t * 4 + 3], cls);
        }
    }
}

// ---------------------------------------------------------------------------
// Kernel 2: row-parallel Jacobi auction (verbatim logic from the fused
// kernel's Phase B1) at 320 threads = 5 waves -> ~3x cheaper barriers than
// the 16-wave monolith. Dumps duals/matching/mask to ws.
// ---------------------------------------------------------------------------
__global__ __launch_bounds__(ATHREADS) void auction_kernel(
    float* __restrict__ ws)
{
    const int b = blockIdx.x;
    const int tid = threadIdx.x;

    __shared__ float s_diag[Tt * Qq];   // 38400 B, [t][q]
    __shared__ float s_v[Qq];
    __shared__ float s_u[Tt + 1];
    __shared__ int   s_colrow[Qq];
    __shared__ unsigned long long s_bid64[Qq];
    __shared__ float s_pm1[ATHREADS], s_pm2[ATHREADS];
    __shared__ int   s_pa[ATHREADS];
    __shared__ unsigned s_mask;

    // stage diag from ws (L2/L3-hot, written by cost_kernel)
    {
        const float4* src = reinterpret_cast<const float4*>(
            ws + DIAG_OFF + (size_t)b * (Tt * Qq));
        float4* dst = reinterpret_cast<float4*>(s_diag);
#pragma unroll 2
        for (int g = tid; g < (Tt * Qq) / 4; g += ATHREADS) dst[g] = src[g];
    }
    if (tid < Qq)  { s_v[tid] = 0.f; s_colrow[tid] = 0; }
    if (tid == 0)  s_mask = 0xffffffffu;
    __syncthreads();

    const int grp = tid / GSZ;          // group 0..31 -> row grp+1
    const int g   = tid - grp * GSZ;    // 0..9
    for (int round = 0; round < AUCTION_ROUNDS; ++round) {
        const unsigned msk = s_mask;    // uniform (read after barrier)
        if (msk == 0) break;            // uniform exit
        for (int jj = tid; jj < Qq; jj += ATHREADS) s_bid64[jj] = 0ull;

        // scan: all unassigned rows in parallel (30 contiguous cols/thread)
        if (grp < Tt && (msk & (1u << grp))) {
            const float* rowp = &s_diag[grp * Qq];
            float m1 = INFINITY, m2 = INFINITY; int a1 = 0;
            const int c0 = g * GCOLS;
#pragma unroll
            for (int jj = 0; jj < GCOLS; ++jj) {
                const int cidx = c0 + jj;
                const float c = rowp[cidx] - s_v[cidx];
                if (c < m1) { m2 = m1; m1 = c; a1 = cidx + 1; }
                else if (c < m2) m2 = c;
            }
            s_pm1[tid] = m1; s_pm2[tid] = m2; s_pa[tid] = a1;
        }
        __syncthreads();

        // leaders: reduce partials, post bid
        float g1 = 0.f, g2 = 0.f; int j1 = 0;
        unsigned long long mypk = 0ull;
        if (tid < Tt && (msk & (1u << tid))) {
            float best = INFINITY, second = INFINITY, bm2 = INFINITY;
            int ba = 0;
            const int base = tid * GSZ;
#pragma unroll
            for (int q = 0; q < GSZ; ++q) {
                const float v = s_pm1[base + q];
                if (v < best) {
                    second = best; best = v;
                    ba = s_pa[base + q]; bm2 = s_pm2[base + q];
                } else if (v < second) second = v;
            }
            g1 = best; g2 = fminf(second, bm2); j1 = ba;
            mypk = ((unsigned long long)(__float_as_uint(g2 - g1) + 1u) << 32)
                   | (unsigned)(0xffffffffu - (unsigned)(tid + 1));
            atomicMax(&s_bid64[j1 - 1], mypk);
        }
        __syncthreads();

        // resolution: winner takes the column; EPS increment from round 2
        if (tid < Tt && (msk & (1u << tid))) {
            const int row = tid + 1;
            const float eps = (round < 2) ? 0.f : AUCTION_EPS;
            if (s_bid64[j1 - 1] == mypk) {      // unique winner of col j1
                const int old = s_colrow[j1 - 1];
                s_colrow[j1 - 1] = row;
                s_v[j1 - 1] -= (g2 - g1) + eps;
                s_u[row] = g2;                  // tight(+eps) + feasible
                atomicAnd(&s_mask, ~(1u << tid));
                if (old) atomicOr(&s_mask, 1u << (old - 1));
            } else {
                s_u[row] = g1;                  // feasible for fallback
            }
        }
        __syncthreads();
    }

    // dump state for the finish kernel
    __syncthreads();
    float* st  = ws + STATE_OFF + (size_t)b * STATE_STRIDE;
    int*   sti = reinterpret_cast<int*>(st + 334);
    for (int jj = tid; jj < Qq; jj += ATHREADS) {
        st[jj]  = s_v[jj];
        sti[jj] = s_colrow[jj];
    }
    if (tid >= 1 && tid <= Tt) st[300 + tid] = s_u[tid];
    if (tid == 0) *reinterpret_cast<unsigned*>(st + 634) = s_mask;
}

// ---------------------------------------------------------------------------
// Kernel 3: deferred-dual Dijkstra fallback (exact, r11 engine, verbatim) +
// matched cross-cost epilogue. Wave 0 does the work; waves 1-3 only stage.
// ---------------------------------------------------------------------------
__global__ __launch_bounds__(FTHREADS) void finish_kernel(
    const float* __restrict__ logits,   // [N,Q,C]
    const float* __restrict__ pboxes,   // [N,Q,4]
    const int*   __restrict__ tlabels,  // [N*T]
    const float* __restrict__ tboxes,   // [N*T,4]
    const float* __restrict__ ws,
    float* __restrict__ out)
{
    const int b = blockIdx.x;
    const int tid = threadIdx.x;

    __shared__ float s_diag[Tt * Qq];
    __shared__ int   pairs[Tt];

    {
        const float4* src = reinterpret_cast<const float4*>(
            ws + DIAG_OFF + (size_t)b * (Tt * Qq));
        float4* dst = reinterpret_cast<float4*>(s_diag);
#pragma unroll 2
        for (int g = tid; g < (Tt * Qq) / 4; g += FTHREADS) dst[g] = src[g];
    }
    __syncthreads();

    if (tid >= 64) return;              // wave 0 only from here
    const int lane = tid;
    const bool inval4 = (lane + 256) >= Qq;

    const float* st  = ws + STATE_OFF + (size_t)b * STATE_STRIDE;
    const int*   sti = reinterpret_cast<const int*>(st + 334);

    float u_reg = (lane >= 1 && lane <= Tt) ? st[300 + lane] : 0.f;
    float v_r[KCOLS]; int p_r[KCOLS];
#pragma unroll
    for (int k = 0; k < KCOLS; ++k) {
        const int jj = lane + 64 * k;
        v_r[k] = (jj < Qq) ? st[jj]  : 0.f;
        p_r[k] = (jj < Qq) ? sti[jj] : 0;
    }
    const unsigned mask0 = *reinterpret_cast<const unsigned*>(st + 634);

    // ---- Dijkstra fallback (verbatim r11 engine) for any leftovers ----
    for (unsigned rem = mask0; rem; rem &= rem - 1) {
        const int i = __ffs(rem);     // row index 1..32

        float minv_r[KCOLS], vmask[KCOLS], am[KCOLS];
        int way_r[KCOLS];
#pragma unroll
        for (int k = 0; k < KCOLS; ++k) {
            minv_r[k] = FLT_MAX; way_r[k] = 0;
            const bool inv = (k == 4) && inval4;
            vmask[k] = inv ? -INFINITY : v_r[k];
            am[k]    = inv ?  INFINITY : 0.f;
        }
        float markg = 0.f;
        int   ent = 0;
        int   j0 = 0, i0 = i;
        float du = 0.f - readlane_f(u_reg, i);   // dent(0) - u[i]
        int   jfinal = 0;
        float Dfinal = 0.f;

        const float* rowp = &s_diag[(i0 - 1) * Qq + lane];
        float c0 = rowp[0], c1 = rowp[64], c2 = rowp[128], c3 = rowp[192],
              c4 = rowp[256];

        while (true) {
            const float cc[KCOLS] = {c0, c1, c2, c3, c4};
            float sv[KCOLS];
#pragma unroll
            for (int k = 0; k < KCOLS; ++k) {
                const float cur = (cc[k] + du) - vmask[k];  // used/invalid -> +inf
                const bool lt = cur < minv_r[k];
                way_r[k]  = lt ? j0  : way_r[k];
                minv_r[k] = lt ? cur : minv_r[k];
                sv[k] = minv_r[k] + am[k];
            }
            float val = sv[0];
            int   kb  = 0;
#pragma unroll
            for (int k = 1; k < KCOLS; ++k)
                if (sv[k] < val) { val = sv[k]; kb = k; }

            const float gmin = wave_min_bcast(val);
            const unsigned long long mask = __ballot(val == gmin);
            const int src = __ffsll((long long)mask) - 1;
            const int colid = lane + 1 + (kb << 6);
            const int pk = (sel5i(p_r, kb) << 16) | colid;
            const int got = __builtin_amdgcn_readlane(pk, src);
            const int j1   = got & 0xffff;
            const int rowm = got >> 16;

            const int k1 = (j1 - 1) >> 6;
            const bool own = (lane == ((j1 - 1) & 63));
#pragma unroll
            for (int k = 0; k < KCOLS; ++k)
                if (own && k == k1) { vmask[k] = -INFINITY; am[k] = INFINITY; }

            if (rowm == 0) { jfinal = j1; Dfinal = gmin; break; }

            i0 = rowm; j0 = j1;
            rowp = &s_diag[(i0 - 1) * Qq + lane];
            c0 = rowp[0]; c1 = rowp[64]; c2 = rowp[128]; c3 = rowp[192];
            c4 = rowp[256];
            du = gmin - readlane_f(u_reg, i0);
            markg = (lane == rowm) ? gmin : markg;
            ent   = (lane == rowm) ? 1    : ent;
        }

#pragma unroll
        for (int k = 0; k < KCOLS; ++k) {
            bool usedk = (am[k] == INFINITY);
            if (k == 4) usedk = usedk && !inval4;
            v_r[k] -= usedk ? (Dfinal - minv_r[k]) : 0.f;
        }
        u_reg += (lane == i) ? Dfinal : (ent ? (Dfinal - markg) : 0.f);

        int jj = jfinal;
        while (jj) {
            const int ow = (jj - 1) & 63, kk = (jj - 1) >> 6;
            const int jprev = __builtin_amdgcn_readlane(sel5i(way_r, kk), ow);
            int pnew;
            if (jprev == 0) pnew = i;
            else pnew = __builtin_amdgcn_readlane(sel5i(p_r, (jprev - 1) >> 6),
                                                  (jprev - 1) & 63);
            const bool own = (lane == ow);
#pragma unroll
            for (int k = 0; k < KCOLS; ++k) if (own && k == kk) p_r[k] = pnew;
            jj = jprev;
        }
    }

    // publish assignment: q_of_t
#pragma unroll
    for (int k = 0; k < KCOLS; ++k)
        if (p_r[k]) pairs[p_r[k] - 1] = lane + 64 * k;
    __threadfence_block();

    // ---- matched cross costs (GLOBAL-target quirk preserved) ----
    float part = 0.f;
    if (lane < Tt) {
        const int q = pairs[lane];                        // matched query
        const float2 mi =
            reinterpret_cast<const float2*>(ws + MXIS_OFF)[b * Qq + q];
        const float cls =
            -__expf(logits[((size_t)(b * Qq) + q) * Cc + tlabels[lane]] - mi.x) * mi.y;
        const float4 pbv = reinterpret_cast<const float4*>(pboxes)[b * Qq + q];
        const float4 tbv = reinterpret_cast<const float4*>(tboxes)[lane];  // GLOBAL t=lane
        part = det_cost_real(pbv.x, pbv.y, pbv.z, pbv.w,
                             tbv.x, tbv.y, tbv.z, tbv.w, cls);
    }
    for (int off = 32; off > 0; off >>= 1) part += __shfl_down(part, off);
    if (lane == 0) atomicAdd(out, part);
}

extern "C" void kernel_launch(void* const* d_in, const int* in_sizes, int n_in,
                              void* d_out, int out_size, void* d_ws, size_t ws_size,
                              hipStream_t stream) {
    const float* logits  = (const float*)d_in[0];   // [32,300,92] f32
    const float* pboxes  = (const float*)d_in[1];   // [32,300,4]  f32
    const int*   tlabels = (const int*)d_in[2];     // [1024]      int
    const float* tboxes  = (const float*)d_in[3];   // [1024,4]    f32
    float* out = (float*)d_out;                     // scalar f32
    float* ws  = (float*)d_ws;                      // >= 1.4 MB used

    (void)hipMemsetAsync(out, 0, sizeof(float), stream);
    cost_kernel<<<Nn * SLICES, CTHREADS, 0, stream>>>(logits, pboxes, tlabels,
                                                      tboxes, ws);
    auction_kernel<<<Nn, ATHREADS, 0, stream>>>(ws);
    finish_kernel<<<Nn, FTHREADS, 0, stream>>>(logits, pboxes, tlabels,
                                               tboxes, ws, out);
}

// Round 3
// 77.730 us; speedup vs baseline: 1.0501x; 1.0501x over previous
//
#include <hip/hip_runtime.h>
#include <cfloat>
#include <cmath>

// Problem constants (from reference)
#define Nn 32
#define Qq 300
#define Cc 92
#define Tt 32
#define KCOLS 5     // ceil(300/64) columns owned per lane (Dijkstra fallback)
#define GSZ 10      // threads per row-group in the auction scan
#define GCOLS 30    // contiguous cols per scan thread (10*30 = 300)
#define AUCTION_ROUNDS 10
#define AUCTION_EPS 1e-3f

#define SLICES 8            // query slices per batch in cost_kernel
#define RPS 38              // rows (queries) per slice: 8*38 = 304 >= 300
#define CTHREADS 256
#define MTHREADS 320        // 5 waves: auction scan needs 320; wave 0 finishes

// Workspace layout (floats). Fully rewritten every launch (ws gets poisoned).
#define DIAG_OFF   0                        // [N][T][Q]  = 307200 f
#define MXIS_OFF   (Nn * Tt * Qq)           // [N][Q] float2 = 19200 f

// ---------------------------------------------------------------------------
// DPP full-wave (64-lane) float min, broadcast to all lanes (~6 dep. v_min).
// Used only in the Dijkstra fallback.
// ---------------------------------------------------------------------------
__device__ inline float wave_min_bcast(float x) {
#define DPPMIN(ctrl) { int _t = __builtin_amdgcn_update_dpp( \
        __float_as_int(x), __float_as_int(x), ctrl, 0xf, 0xf, false); \
        x = fminf(x, __int_as_float(_t)); }
    DPPMIN(0x111) DPPMIN(0x112) DPPMIN(0x114) DPPMIN(0x118)
    DPPMIN(0x142) DPPMIN(0x143)
#undef DPPMIN
    return __int_as_float(__builtin_amdgcn_readlane(__float_as_int(x), 63));
}

// Select a[k] for runtime k (cndmask chain, no scratch).
__device__ inline int sel5i(const int a[KCOLS], int k) {
    int r = a[0];
    if (k == 1) r = a[1];
    if (k == 2) r = a[2];
    if (k == 3) r = a[3];
    if (k == 4) r = a[4];
    return r;
}

__device__ inline float readlane_f(float v, int lane) {
    return __int_as_float(__builtin_amdgcn_readlane(__float_as_int(v), lane));
}

// cost = 5*L1 + cls - 2*giou   (cls = -softmax_prob[label], passed in).
// Operation order identical to the verified baseline's det_cost.
__device__ inline float det_cost_real(float cx, float cy, float w, float h,
                                      float bcx, float bcy, float bw, float bh,
                                      float cls) {
    const float ax0 = cx - 0.5f * w, ay0 = cy - 0.5f * h;
    const float ax1 = cx + 0.5f * w, ay1 = cy + 0.5f * h;
    const float areaA = (ax1 - ax0) * (ay1 - ay0);

    const float l1 = fabsf(cx - bcx) + fabsf(cy - bcy) +
                     fabsf(w - bw) + fabsf(h - bh);

    const float bx0 = bcx - 0.5f * bw, by0 = bcy - 0.5f * bh;
    const float bx1 = bcx + 0.5f * bw, by1 = bcy + 0.5f * bh;
    const float areaB = (bx1 - bx0) * (by1 - by0);

    const float ltx = fmaxf(ax0, bx0), lty = fmaxf(ay0, by0);
    const float rbx = fminf(ax1, bx1), rby = fminf(ay1, by1);
    const float iw = fmaxf(rbx - ltx, 0.f), ih = fmaxf(rby - lty, 0.f);
    const float inter = iw * ih;
    const float uni = areaA + areaB - inter;
    const float iou = inter / uni;

    const float ex0 = fminf(ax0, bx0), ey0 = fminf(ay0, by0);
    const float ex1 = fmaxf(ax1, bx1), ey1 = fmaxf(ay1, by1);
    const float areaC = fmaxf(ex1 - ex0, 0.f) * fmaxf(ey1 - ey0, 0.f);
    const float giou = iou - (areaC - uni) / areaC;

    return 5.f * l1 + cls - 2.f * giou;
}

// ---------------------------------------------------------------------------
// Kernel 1: cost matrix + softmax stats at 256-block parallelism.
// Block (b, s) owns queries [s*38, s*38+38) of batch b. Softmax is computed
// 4-lanes-per-row with the exact same partial-accumulator decomposition as
// the original fused kernel's softmax_lds (bit-identical mx / inv_s).
// Block 0 also zeroes the output accumulator (stream order protects it).
// ---------------------------------------------------------------------------
__global__ __launch_bounds__(CTHREADS) void cost_kernel(
    const float* __restrict__ logits,   // [N,Q,C]
    const float* __restrict__ pboxes,   // [N,Q,4]
    const int*   __restrict__ tlabels,  // [N*T]
    const float* __restrict__ tboxes,   // [N*T,4]
    float* __restrict__ ws,
    float* __restrict__ out)
{
    const int bs = blockIdx.x;
    const int b = bs >> 3, s = bs & 7;
    const int q0 = s * RPS;
    const int nq = min(RPS, Qq - q0);   // 38, except 34 for s==7

    __shared__ float2 s_mxis[RPS];
    __shared__ float  s_tb[Tt * 4];
    __shared__ int    s_tl[Tt];

    const int tid = threadIdx.x;
    if (bs == 0 && tid == 0) *out = 0.f;   // replaces the memset dispatch
    if (tid < Tt * 4) s_tb[tid] = tboxes[b * Tt * 4 + tid];
    if (tid < Tt)     s_tl[tid] = tlabels[b * Tt + tid];

    // ---- softmax stats: 4 lanes per query row, bit-identical recombine ----
    const int r = tid >> 2, j = tid & 3;
    if (r < nq) {
        const float* row = logits + ((size_t)(b * Qq) + q0 + r) * Cc;
        float mj = -FLT_MAX;
#pragma unroll
        for (int c = 0; c < Cc; c += 4) mj = fmaxf(mj, row[c + j]);
        const float ma = fmaxf(mj, __shfl_xor(mj, 1, 4));
        const float mx = fmaxf(ma, __shfl_xor(ma, 2, 4));   // = max(max(m0,m1),max(m2,m3))
        float sj = 0.f;
#pragma unroll
        for (int c = 0; c < Cc; c += 4) sj += __expf(row[c + j] - mx);
        const float sa   = sj + __shfl_xor(sj, 1, 4);       // s0+s1 | s2+s3
        const float ssum = sa + __shfl_xor(sa, 2, 4);       // (s0+s1)+(s2+s3)
        if (j == 0) {
            const float2 mi = make_float2(mx, 1.f / ssum);
            s_mxis[r] = mi;
            reinterpret_cast<float2*>(ws + MXIS_OFF)[b * Qq + q0 + r] = mi;
        }
    }
    __syncthreads();

    // ---- diag cost entries for this slice: 32*nq entries across 256 thr ----
    float* diagb = ws + DIAG_OFF + (size_t)b * (Tt * Qq);
    for (int e = tid; e < Tt * RPS; e += CTHREADS) {
        const int t = e / RPS, lq = e - t * RPS;
        const int q = q0 + lq;
        if (q < Qq) {
            const float2 mi = s_mxis[lq];
            const float cls =
                -__expf(logits[((size_t)(b * Qq) + q) * Cc + s_tl[t]] - mi.x) * mi.y;
            const float4 pbv = reinterpret_cast<const float4*>(pboxes)[b * Qq + q];
            diagb[t * Qq + q] = det_cost_real(pbv.x, pbv.y, pbv.z, pbv.w,
                                              s_tb[t * 4 + 0], s_tb[t * 4 + 1],
                                              s_tb[t * 4 + 2], s_tb[t * 4 + 3], cls);
        }
    }
}

// ---------------------------------------------------------------------------
// Kernel 2: auction + Dijkstra fallback + epilogue, one block per batch.
// The auction's resolution step runs entirely in wave 0 (tid<32), so the
// Dijkstra engine reads s_v/s_u/s_colrow/s_mask straight from LDS — no
// global dump/reload, no extra kernel boundary.
// ---------------------------------------------------------------------------
__global__ __launch_bounds__(MTHREADS) void match_kernel(
    const float* __restrict__ logits,   // [N,Q,C]
    const float* __restrict__ pboxes,   // [N,Q,4]
    const int*   __restrict__ tlabels,  // [N*T]
    const float* __restrict__ tboxes,   // [N*T,4]
    const float* __restrict__ ws,
    float* __restrict__ out)
{
    const int b = blockIdx.x;
    const int tid = threadIdx.x;

    __shared__ float s_diag[Tt * Qq];   // 38400 B, [t][q]
    __shared__ float s_v[Qq];
    __shared__ float s_u[Tt + 1];
    __shared__ int   s_colrow[Qq];
    __shared__ unsigned long long s_bid64[Qq];
    __shared__ float s_pm1[MTHREADS], s_pm2[MTHREADS];
    __shared__ int   s_pa[MTHREADS];
    __shared__ int   pairs[Tt];
    __shared__ unsigned s_mask;

    // stage diag from ws (L2/L3-hot, written by cost_kernel)
    {
        const float4* src = reinterpret_cast<const float4*>(
            ws + DIAG_OFF + (size_t)b * (Tt * Qq));
        float4* dst = reinterpret_cast<float4*>(s_diag);
#pragma unroll 2
        for (int g = tid; g < (Tt * Qq) / 4; g += MTHREADS) dst[g] = src[g];
    }
    if (tid < Qq)  { s_v[tid] = 0.f; s_colrow[tid] = 0; }
    if (tid == 0)  s_mask = 0xffffffffu;
    __syncthreads();

    // ---------------- Phase B1: row-parallel Jacobi auction ----------------
    const int grp = tid / GSZ;          // group 0..31 -> row grp+1
    const int g   = tid - grp * GSZ;    // 0..9
    for (int round = 0; round < AUCTION_ROUNDS; ++round) {
        const unsigned msk = s_mask;    // uniform (read after barrier)
        if (msk == 0) break;            // uniform exit
        for (int jj = tid; jj < Qq; jj += MTHREADS) s_bid64[jj] = 0ull;

        // scan: all unassigned rows in parallel (30 contiguous cols/thread)
        if (grp < Tt && (msk & (1u << grp))) {
            const float* rowp = &s_diag[grp * Qq];
            float m1 = INFINITY, m2 = INFINITY; int a1 = 0;
            const int c0 = g * GCOLS;
#pragma unroll
            for (int jj = 0; jj < GCOLS; ++jj) {
                const int cidx = c0 + jj;
                const float c = rowp[cidx] - s_v[cidx];
                if (c < m1) { m2 = m1; m1 = c; a1 = cidx + 1; }
                else if (c < m2) m2 = c;
            }
            s_pm1[tid] = m1; s_pm2[tid] = m2; s_pa[tid] = a1;
        }
        __syncthreads();

        // leaders: reduce partials, post bid
        float g1 = 0.f, g2 = 0.f; int j1 = 0;
        unsigned long long mypk = 0ull;
        if (tid < Tt && (msk & (1u << tid))) {
            float best = INFINITY, second = INFINITY, bm2 = INFINITY;
            int ba = 0;
            const int base = tid * GSZ;
#pragma unroll
            for (int q = 0; q < GSZ; ++q) {
                const float v = s_pm1[base + q];
                if (v < best) {
                    second = best; best = v;
                    ba = s_pa[base + q]; bm2 = s_pm2[base + q];
                } else if (v < second) second = v;
            }
            g1 = best; g2 = fminf(second, bm2); j1 = ba;
            mypk = ((unsigned long long)(__float_as_uint(g2 - g1) + 1u) << 32)
                   | (unsigned)(0xffffffffu - (unsigned)(tid + 1));
            atomicMax(&s_bid64[j1 - 1], mypk);
        }
        __syncthreads();

        // resolution: winner takes the column; EPS increment from round 2
        if (tid < Tt && (msk & (1u << tid))) {
            const int row = tid + 1;
            const float eps = (round < 2) ? 0.f : AUCTION_EPS;
            if (s_bid64[j1 - 1] == mypk) {      // unique winner of col j1
                const int old = s_colrow[j1 - 1];
                s_colrow[j1 - 1] = row;
                s_v[j1 - 1] -= (g2 - g1) + eps;
                s_u[row] = g2;                  // tight(+eps) + feasible
                atomicAnd(&s_mask, ~(1u << tid));
                if (old) atomicOr(&s_mask, 1u << (old - 1));
            } else {
                s_u[row] = g1;                  // feasible for fallback
            }
        }
        __syncthreads();
    }

    // ---------------- wave 0 finishes: Dijkstra + epilogue ----------------
    if (tid >= 64) return;              // all barriers are behind us
    const int lane = tid;
    const bool inval4 = (lane + 256) >= Qq;

    // load duals/matching into wave-0 registers straight from LDS.
    // (resolution writes came from wave-0 lanes; same-wave LDS is
    //  program-order coherent, no barrier needed)
    float u_reg = (lane >= 1 && lane <= Tt) ? s_u[lane] : 0.f;
    float v_r[KCOLS]; int p_r[KCOLS];
#pragma unroll
    for (int k = 0; k < KCOLS; ++k) {
        const int jj = lane + 64 * k;
        v_r[k] = (jj < Qq) ? s_v[jj] : 0.f;
        p_r[k] = (jj < Qq) ? s_colrow[jj] : 0;
    }
    const unsigned mask0 = s_mask;

    // ---- Dijkstra fallback (verbatim r11 engine) for any leftovers ----
    for (unsigned rem = mask0; rem; rem &= rem - 1) {
        const int i = __ffs(rem);     // row index 1..32

        float minv_r[KCOLS], vmask[KCOLS], am[KCOLS];
        int way_r[KCOLS];
#pragma unroll
        for (int k = 0; k < KCOLS; ++k) {
            minv_r[k] = FLT_MAX; way_r[k] = 0;
            const bool inv = (k == 4) && inval4;
            vmask[k] = inv ? -INFINITY : v_r[k];
            am[k]    = inv ?  INFINITY : 0.f;
        }
        float markg = 0.f;
        int   ent = 0;
        int   j0 = 0, i0 = i;
        float du = 0.f - readlane_f(u_reg, i);   // dent(0) - u[i]
        int   jfinal = 0;
        float Dfinal = 0.f;

        const float* rowp = &s_diag[(i0 - 1) * Qq + lane];
        float c0 = rowp[0], c1 = rowp[64], c2 = rowp[128], c3 = rowp[192],
              c4 = rowp[256];

        while (true) {
            const float cc[KCOLS] = {c0, c1, c2, c3, c4};
            float sv[KCOLS];
#pragma unroll
            for (int k = 0; k < KCOLS; ++k) {
                const float cur = (cc[k] + du) - vmask[k];  // used/invalid -> +inf
                const bool lt = cur < minv_r[k];
                way_r[k]  = lt ? j0  : way_r[k];
                minv_r[k] = lt ? cur : minv_r[k];
                sv[k] = minv_r[k] + am[k];
            }
            float val = sv[0];
            int   kb  = 0;
#pragma unroll
            for (int k = 1; k < KCOLS; ++k)
                if (sv[k] < val) { val = sv[k]; kb = k; }

            const float gmin = wave_min_bcast(val);
            const unsigned long long mask = __ballot(val == gmin);
            const int src = __ffsll((long long)mask) - 1;
            const int colid = lane + 1 + (kb << 6);
            const int pk = (sel5i(p_r, kb) << 16) | colid;
            const int got = __builtin_amdgcn_readlane(pk, src);
            const int j1   = got & 0xffff;
            const int rowm = got >> 16;

            const int k1 = (j1 - 1) >> 6;
            const bool own = (lane == ((j1 - 1) & 63));
#pragma unroll
            for (int k = 0; k < KCOLS; ++k)
                if (own && k == k1) { vmask[k] = -INFINITY; am[k] = INFINITY; }

            if (rowm == 0) { jfinal = j1; Dfinal = gmin; break; }

            i0 = rowm; j0 = j1;
            rowp = &s_diag[(i0 - 1) * Qq + lane];
            c0 = rowp[0]; c1 = rowp[64]; c2 = rowp[128]; c3 = rowp[192];
            c4 = rowp[256];
            du = gmin - readlane_f(u_reg, i0);
            markg = (lane == rowm) ? gmin : markg;
            ent   = (lane == rowm) ? 1    : ent;
        }

#pragma unroll
        for (int k = 0; k < KCOLS; ++k) {
            bool usedk = (am[k] == INFINITY);
            if (k == 4) usedk = usedk && !inval4;
            v_r[k] -= usedk ? (Dfinal - minv_r[k]) : 0.f;
        }
        u_reg += (lane == i) ? Dfinal : (ent ? (Dfinal - markg) : 0.f);

        int jj = jfinal;
        while (jj) {
            const int ow = (jj - 1) & 63, kk = (jj - 1) >> 6;
            const int jprev = __builtin_amdgcn_readlane(sel5i(way_r, kk), ow);
            int pnew;
            if (jprev == 0) pnew = i;
            else pnew = __builtin_amdgcn_readlane(sel5i(p_r, (jprev - 1) >> 6),
                                                  (jprev - 1) & 63);
            const bool own = (lane == ow);
#pragma unroll
            for (int k = 0; k < KCOLS; ++k) if (own && k == kk) p_r[k] = pnew;
            jj = jprev;
        }
    }

    // publish assignment: q_of_t
#pragma unroll
    for (int k = 0; k < KCOLS; ++k)
        if (p_r[k]) pairs[p_r[k] - 1] = lane + 64 * k;
    __threadfence_block();

    // ---- matched cross costs (GLOBAL-target quirk preserved) ----
    float part = 0.f;
    if (lane < Tt) {
        const int q = pairs[lane];                        // matched query
        const float2 mi =
            reinterpret_cast<const float2*>(ws + MXIS_OFF)[b * Qq + q];
        const float cls =
            -__expf(logits[((size_t)(b * Qq) + q) * Cc + tlabels[lane]] - mi.x) * mi.y;
        const float4 pbv = reinterpret_cast<const float4*>(pboxes)[b * Qq + q];
        const float4 tbv = reinterpret_cast<const float4*>(tboxes)[lane];  // GLOBAL t=lane
        part = det_cost_real(pbv.x, pbv.y, pbv.z, pbv.w,
                             tbv.x, tbv.y, tbv.z, tbv.w, cls);
    }
    for (int off = 32; off > 0; off >>= 1) part += __shfl_down(part, off);
    if (lane == 0) atomicAdd(out, part);
}

extern "C" void kernel_launch(void* const* d_in, const int* in_sizes, int n_in,
                              void* d_out, int out_size, void* d_ws, size_t ws_size,
                              hipStream_t stream) {
    const float* logits  = (const float*)d_in[0];   // [32,300,92] f32
    const float* pboxes  = (const float*)d_in[1];   // [32,300,4]  f32
    const int*   tlabels = (const int*)d_in[2];     // [1024]      int
    const float* tboxes  = (const float*)d_in[3];   // [1024,4]    f32
    float* out = (float*)d_out;                     // scalar f32
    float* ws  = (float*)d_ws;                      // ~1.3 MB used

    cost_kernel<<<Nn * SLICES, CTHREADS, 0, stream>>>(logits, pboxes, tlabels,
                                                      tboxes, ws, out);
    match_kernel<<<Nn, MTHREADS, 0, stream>>>(logits, pboxes, tlabels,
                                              tboxes, ws, out);
}

// Round 5
// 76.513 us; speedup vs baseline: 1.0668x; 1.0159x over previous
//
#include <hip/hip_runtime.h>
#include <cfloat>
#include <cmath>

// Problem constants (from reference)
#define Nn 32
#define Qq 300
#define Cc 92
#define Tt 32
#define KCOLS 5     // ceil(300/64) columns owned per lane (Dijkstra fallback)
#define GSZ 10      // threads per row-group in the auction scan
#define GCOLS 30    // contiguous cols per scan thread (10*30 = 300)
#define AUCTION_ROUNDS 24   // rounds 0-9 identical to verified kernel; 10-23
                            // continue with eps=0 (tight assignments only) to
                            // shrink the serial Dijkstra leftover set
#define AUCTION_EPS 1e-3f

#define SLICES 8            // query slices per batch in cost_kernel
#define RPS 38              // rows (queries) per slice: 8*38 = 304 >= 300
#define CTHREADS 256
#define MTHREADS 320        // 5 waves: auction scan needs 320; wave 0 finishes

// Workspace layout (floats). Fully rewritten every launch (ws gets poisoned).
#define DIAG_OFF   0                        // [N][T][Q]  = 307200 f
#define MXIS_OFF   (Nn * Tt * Qq)           // [N][Q] float2 = 19200 f

// ---------------------------------------------------------------------------
// DPP full-wave (64-lane) float min, broadcast to all lanes (~6 dep. v_min).
// Used only in the Dijkstra fallback.
// ---------------------------------------------------------------------------
__device__ inline float wave_min_bcast(float x) {
#define DPPMIN(ctrl) { int _t = __builtin_amdgcn_update_dpp( \
        __float_as_int(x), __float_as_int(x), ctrl, 0xf, 0xf, false); \
        x = fminf(x, __int_as_float(_t)); }
    DPPMIN(0x111) DPPMIN(0x112) DPPMIN(0x114) DPPMIN(0x118)
    DPPMIN(0x142) DPPMIN(0x143)
#undef DPPMIN
    return __int_as_float(__builtin_amdgcn_readlane(__float_as_int(x), 63));
}

// Select a[k] for runtime k (cndmask chain, no scratch).
__device__ inline int sel5i(const int a[KCOLS], int k) {
    int r = a[0];
    if (k == 1) r = a[1];
    if (k == 2) r = a[2];
    if (k == 3) r = a[3];
    if (k == 4) r = a[4];
    return r;
}

__device__ inline float readlane_f(float v, int lane) {
    return __int_as_float(__builtin_amdgcn_readlane(__float_as_int(v), lane));
}

// cost = 5*L1 + cls - 2*giou   (cls = -softmax_prob[label], passed in).
// Operation order identical to the verified baseline's det_cost.
__device__ inline float det_cost_real(float cx, float cy, float w, float h,
                                      float bcx, float bcy, float bw, float bh,
                                      float cls) {
    const float ax0 = cx - 0.5f * w, ay0 = cy - 0.5f * h;
    const float ax1 = cx + 0.5f * w, ay1 = cy + 0.5f * h;
    const float areaA = (ax1 - ax0) * (ay1 - ay0);

    const float l1 = fabsf(cx - bcx) + fabsf(cy - bcy) +
                     fabsf(w - bw) + fabsf(h - bh);

    const float bx0 = bcx - 0.5f * bw, by0 = bcy - 0.5f * bh;
    const float bx1 = bcx + 0.5f * bw, by1 = bcy + 0.5f * bh;
    const float areaB = (bx1 - bx0) * (by1 - by0);

    const float ltx = fmaxf(ax0, bx0), lty = fmaxf(ay0, by0);
    const float rbx = fminf(ax1, bx1), rby = fminf(ay1, by1);
    const float iw = fmaxf(rbx - ltx, 0.f), ih = fmaxf(rby - lty, 0.f);
    const float inter = iw * ih;
    const float uni = areaA + areaB - inter;
    const float iou = inter / uni;

    const float ex0 = fminf(ax0, bx0), ey0 = fminf(ay0, by0);
    const float ex1 = fmaxf(ax1, bx1), ey1 = fmaxf(ay1, by1);
    const float areaC = fmaxf(ex1 - ex0, 0.f) * fmaxf(ey1 - ey0, 0.f);
    const float giou = iou - (areaC - uni) / areaC;

    return 5.f * l1 + cls - 2.f * giou;
}

// ---------------------------------------------------------------------------
// Kernel 1: cost matrix + softmax stats at 256-block parallelism.
// Block (b, s) owns queries [s*38, s*38+38) of batch b. Softmax is computed
// 4-lanes-per-row with the exact same partial-accumulator decomposition as
// the original fused kernel's softmax_lds (bit-identical mx / inv_s).
// Block 0 also zeroes the output accumulator (stream order protects it).
// ---------------------------------------------------------------------------
__global__ __launch_bounds__(CTHREADS) void cost_kernel(
    const float* __restrict__ logits,   // [N,Q,C]
    const float* __restrict__ pboxes,   // [N,Q,4]
    const int*   __restrict__ tlabels,  // [N*T]
    const float* __restrict__ tboxes,   // [N*T,4]
    float* __restrict__ ws,
    float* __restrict__ out)
{
    const int bs = blockIdx.x;
    const int b = bs >> 3, s = bs & 7;
    const int q0 = s * RPS;
    const int nq = min(RPS, Qq - q0);   // 38, except 34 for s==7

    __shared__ float2 s_mxis[RPS];
    __shared__ float  s_tb[Tt * 4];
    __shared__ int    s_tl[Tt];

    const int tid = threadIdx.x;
    if (bs == 0 && tid == 0) *out = 0.f;   // replaces the memset dispatch
    if (tid < Tt * 4) s_tb[tid] = tboxes[b * Tt * 4 + tid];
    if (tid < Tt)     s_tl[tid] = tlabels[b * Tt + tid];

    // ---- softmax stats: 4 lanes per query row, bit-identical recombine ----
    const int r = tid >> 2, j = tid & 3;
    if (r < nq) {
        const float* row = logits + ((size_t)(b * Qq) + q0 + r) * Cc;
        float mj = -FLT_MAX;
#pragma unroll
        for (int c = 0; c < Cc; c += 4) mj = fmaxf(mj, row[c + j]);
        const float ma = fmaxf(mj, __shfl_xor(mj, 1, 4));
        const float mx = fmaxf(ma, __shfl_xor(ma, 2, 4));   // = max(max(m0,m1),max(m2,m3))
        float sj = 0.f;
#pragma unroll
        for (int c = 0; c < Cc; c += 4) sj += __expf(row[c + j] - mx);
        const float sa   = sj + __shfl_xor(sj, 1, 4);       // s0+s1 | s2+s3
        const float ssum = sa + __shfl_xor(sa, 2, 4);       // (s0+s1)+(s2+s3)
        if (j == 0) {
            const float2 mi = make_float2(mx, 1.f / ssum);
            s_mxis[r] = mi;
            reinterpret_cast<float2*>(ws + MXIS_OFF)[b * Qq + q0 + r] = mi;
        }
    }
    __syncthreads();

    // ---- diag cost entries for this slice: 32*nq entries across 256 thr ----
    float* diagb = ws + DIAG_OFF + (size_t)b * (Tt * Qq);
    for (int e = tid; e < Tt * RPS; e += CTHREADS) {
        const int t = e / RPS, lq = e - t * RPS;
        const int q = q0 + lq;
        if (q < Qq) {
            const float2 mi = s_mxis[lq];
            const float cls =
                -__expf(logits[((size_t)(b * Qq) + q) * Cc + s_tl[t]] - mi.x) * mi.y;
            const float4 pbv = reinterpret_cast<const float4*>(pboxes)[b * Qq + q];
            diagb[t * Qq + q] = det_cost_real(pbv.x, pbv.y, pbv.z, pbv.w,
                                              s_tb[t * 4 + 0], s_tb[t * 4 + 1],
                                              s_tb[t * 4 + 2], s_tb[t * 4 + 3], cls);
        }
    }
}

// ---------------------------------------------------------------------------
// Kernel 2: auction + Dijkstra fallback + epilogue, one block per batch.
// Auction rounds 0-9 are bit-identical to the verified kernel; rounds 10-23
// continue with eps=0 so every additional assignment is TIGHT (reduced cost
// exactly 0) — strictly safe for the exact Dijkstra phase, which then has a
// smaller (often empty) leftover set to process serially.
// ---------------------------------------------------------------------------
__global__ __launch_bounds__(MTHREADS) void match_kernel(
    const float* __restrict__ logits,   // [N,Q,C]
    const float* __restrict__ pboxes,   // [N,Q,4]
    const int*   __restrict__ tlabels,  // [N*T]
    const float* __restrict__ tboxes,   // [N*T,4]
    const float* __restrict__ ws,
    float* __restrict__ out)
{
    const int b = blockIdx.x;
    const int tid = threadIdx.x;

    __shared__ float s_diag[Tt * Qq];   // 38400 B, [t][q]
    __shared__ float s_v[Qq];
    __shared__ float s_u[Tt + 1];
    __shared__ int   s_colrow[Qq];
    __shared__ unsigned long long s_bid64[Qq];
    __shared__ float s_pm1[MTHREADS], s_pm2[MTHREADS];
    __shared__ int   s_pa[MTHREADS];
    __shared__ int   pairs[Tt];
    __shared__ unsigned s_mask;

    // stage diag from ws (L2/L3-hot, written by cost_kernel)
    {
        const float4* src = reinterpret_cast<const float4*>(
            ws + DIAG_OFF + (size_t)b * (Tt * Qq));
        float4* dst = reinterpret_cast<float4*>(s_diag);
#pragma unroll 2
        for (int g = tid; g < (Tt * Qq) / 4; g += MTHREADS) dst[g] = src[g];
    }
    if (tid < Qq)  { s_v[tid] = 0.f; s_colrow[tid] = 0; }
    if (tid == 0)  s_mask = 0xffffffffu;
    __syncthreads();

    // ---------------- Phase B1: row-parallel Jacobi auction ----------------
    const int grp = tid / GSZ;          // group 0..31 -> row grp+1
    const int g   = tid - grp * GSZ;    // 0..9
    for (int round = 0; round < AUCTION_ROUNDS; ++round) {
        const unsigned msk = s_mask;    // uniform (read after barrier)
        if (msk == 0) break;            // uniform exit
        for (int jj = tid; jj < Qq; jj += MTHREADS) s_bid64[jj] = 0ull;

        // scan: all unassigned rows in parallel (30 contiguous cols/thread)
        if (grp < Tt && (msk & (1u << grp))) {
            const float* rowp = &s_diag[grp * Qq];
            float m1 = INFINITY, m2 = INFINITY; int a1 = 0;
            const int c0 = g * GCOLS;
#pragma unroll
            for (int jj = 0; jj < GCOLS; ++jj) {
                const int cidx = c0 + jj;
                const float c = rowp[cidx] - s_v[cidx];
                if (c < m1) { m2 = m1; m1 = c; a1 = cidx + 1; }
                else if (c < m2) m2 = c;
            }
            s_pm1[tid] = m1; s_pm2[tid] = m2; s_pa[tid] = a1;
        }
        __syncthreads();

        // leaders: reduce partials, post bid
        float g1 = 0.f, g2 = 0.f; int j1 = 0;
        unsigned long long mypk = 0ull;
        if (tid < Tt && (msk & (1u << tid))) {
            float best = INFINITY, second = INFINITY, bm2 = INFINITY;
            int ba = 0;
            const int base = tid * GSZ;
#pragma unroll
            for (int q = 0; q < GSZ; ++q) {
                const float v = s_pm1[base + q];
                if (v < best) {
                    second = best; best = v;
                    ba = s_pa[base + q]; bm2 = s_pm2[base + q];
                } else if (v < second) second = v;
            }
            g1 = best; g2 = fminf(second, bm2); j1 = ba;
            mypk = ((unsigned long long)(__float_as_uint(g2 - g1) + 1u) << 32)
                   | (unsigned)(0xffffffffu - (unsigned)(tid + 1));
            atomicMax(&s_bid64[j1 - 1], mypk);
        }
        __syncthreads();

        // resolution: winner takes the column.
        // eps schedule: rounds 0-1 eps=0 (warmup), 2-9 eps=AUCTION_EPS
        // (identical to verified kernel), >=10 eps=0 (tight-only extension).
        if (tid < Tt && (msk & (1u << tid))) {
            const int row = tid + 1;
            const float eps = (round < 2 || round >= 10) ? 0.f : AUCTION_EPS;
            if (s_bid64[j1 - 1] == mypk) {      // unique winner of col j1
                const int old = s_colrow[j1 - 1];
                s_colrow[j1 - 1] = row;
                s_v[j1 - 1] -= (g2 - g1) + eps;
                s_u[row] = g2;                  // tight(+eps) + feasible
                atomicAnd(&s_mask, ~(1u << tid));
                if (old) atomicOr(&s_mask, 1u << (old - 1));
            } else {
                s_u[row] = g1;                  // feasible for fallback
            }
        }
        __syncthreads();
    }

    // ---------------- wave 0 finishes: Dijkstra + epilogue ----------------
    if (tid >= 64) return;              // all barriers are behind us
    const int lane = tid;
    const bool inval4 = (lane + 256) >= Qq;

    // load duals/matching into wave-0 registers straight from LDS.
    float u_reg = (lane >= 1 && lane <= Tt) ? s_u[lane] : 0.f;
    float v_r[KCOLS]; int p_r[KCOLS];
#pragma unroll
    for (int k = 0; k < KCOLS; ++k) {
        const int jj = lane + 64 * k;
        v_r[k] = (jj < Qq) ? s_v[jj] : 0.f;
        p_r[k] = (jj < Qq) ? s_colrow[jj] : 0;
    }
    const unsigned mask0 = s_mask;

    // ---- Dijkstra fallback (verbatim r11 engine) for any leftovers ----
    for (unsigned rem = mask0; rem; rem &= rem - 1) {
        const int i = __ffs(rem);     // row index 1..32

        float minv_r[KCOLS], vmask[KCOLS], am[KCOLS];
        int way_r[KCOLS];
#pragma unroll
        for (int k = 0; k < KCOLS; ++k) {
            minv_r[k] = FLT_MAX; way_r[k] = 0;
            const bool inv = (k == 4) && inval4;
            vmask[k] = inv ? -INFINITY : v_r[k];
            am[k]    = inv ?  INFINITY : 0.f;
        }
        float markg = 0.f;
        int   ent = 0;
        int   j0 = 0, i0 = i;
        float du = 0.f - readlane_f(u_reg, i);   // dent(0) - u[i]
        int   jfinal = 0;
        float Dfinal = 0.f;

        const float* rowp = &s_diag[(i0 - 1) * Qq + lane];
        float c0 = rowp[0], c1 = rowp[64], c2 = rowp[128], c3 = rowp[192],
              c4 = rowp[256];

        while (true) {
            const float cc[KCOLS] = {c0, c1, c2, c3, c4};
            float sv[KCOLS];
#pragma unroll
            for (int k = 0; k < KCOLS; ++k) {
                const float cur = (cc[k] + du) - vmask[k];  // used/invalid -> +inf
                const bool lt = cur < minv_r[k];
                way_r[k]  = lt ? j0  : way_r[k];
                minv_r[k] = lt ? cur : minv_r[k];
                sv[k] = minv_r[k] + am[k];
            }
            float val = sv[0];
            int   kb  = 0;
#pragma unroll
            for (int k = 1; k < KCOLS; ++k)
                if (sv[k] < val) { val = sv[k]; kb = k; }

            const float gmin = wave_min_bcast(val);
            const unsigned long long mask = __ballot(val == gmin);
            const int src = __ffsll((long long)mask) - 1;
            const int colid = lane + 1 + (kb << 6);
            const int pk = (sel5i(p_r, kb) << 16) | colid;
            const int got = __builtin_amdgcn_readlane(pk, src);
            const int j1   = got & 0xffff;
            const int rowm = got >> 16;

            const int k1 = (j1 - 1) >> 6;
            const bool own = (lane == ((j1 - 1) & 63));
#pragma unroll
            for (int k = 0; k < KCOLS; ++k)
                if (own && k == k1) { vmask[k] = -INFINITY; am[k] = INFINITY; }

            if (rowm == 0) { jfinal = j1; Dfinal = gmin; break; }

            i0 = rowm; j0 = j1;
            rowp = &s_diag[(i0 - 1) * Qq + lane];
            c0 = rowp[0]; c1 = rowp[64]; c2 = rowp[128]; c3 = rowp[192];
            c4 = rowp[256];
            du = gmin - readlane_f(u_reg, i0);
            markg = (lane == rowm) ? gmin : markg;
            ent   = (lane == rowm) ? 1    : ent;
        }

#pragma unroll
        for (int k = 0; k < KCOLS; ++k) {
            bool usedk = (am[k] == INFINITY);
            if (k == 4) usedk = usedk && !inval4;
            v_r[k] -= usedk ? (Dfinal - minv_r[k]) : 0.f;
        }
        u_reg += (lane == i) ? Dfinal : (ent ? (Dfinal - markg) : 0.f);

        int jj = jfinal;
        while (jj) {
            const int ow = (jj - 1) & 63, kk = (jj - 1) >> 6;
            const int jprev = __builtin_amdgcn_readlane(sel5i(way_r, kk), ow);
            int pnew;
            if (jprev == 0) pnew = i;
            else pnew = __builtin_amdgcn_readlane(sel5i(p_r, (jprev - 1) >> 6),
                                                  (jprev - 1) & 63);
            const bool own = (lane == ow);
#pragma unroll
            for (int k = 0; k < KCOLS; ++k) if (own && k == kk) p_r[k] = pnew;
            jj = jprev;
        }
    }

    // publish assignment: q_of_t
#pragma unroll
    for (int k = 0; k < KCOLS; ++k)
        if (p_r[k]) pairs[p_r[k] - 1] = lane + 64 * k;
    __threadfence_block();

    // ---- matched cross costs (GLOBAL-target quirk preserved) ----
    float part = 0.f;
    if (lane < Tt) {
        const int q = pairs[lane];                        // matched query
        const float2 mi =
            reinterpret_cast<const float2*>(ws + MXIS_OFF)[b * Qq + q];
        const float cls =
            -__expf(logits[((size_t)(b * Qq) + q) * Cc + tlabels[lane]] - mi.x) * mi.y;
        const float4 pbv = reinterpret_cast<const float4*>(pboxes)[b * Qq + q];
        const float4 tbv = reinterpret_cast<const float4*>(tboxes)[lane];  // GLOBAL t=lane
        part = det_cost_real(pbv.x, pbv.y, pbv.z, pbv.w,
                             tbv.x, tbv.y, tbv.z, tbv.w, cls);
    }
    for (int off = 32; off > 0; off >>= 1) part += __shfl_down(part, off);
    if (lane == 0) atomicAdd(out, part);
}

extern "C" void kernel_launch(void* const* d_in, const int* in_sizes, int n_in,
                              void* d_out, int out_size, void* d_ws, size_t ws_size,
                              hipStream_t stream) {
    const float* logits  = (const float*)d_in[0];   // [32,300,92] f32
    const float* pboxes  = (const float*)d_in[1];   // [32,300,4]  f32
    const int*   tlabels = (const int*)d_in[2];     // [1024]      int
    const float* tboxes  = (const float*)d_in[3];   // [1024,4]    f32
    float* out = (float*)d_out;                     // scalar f32
    float* ws  = (float*)d_ws;                      // ~1.3 MB used

    cost_kernel<<<Nn * SLICES, CTHREADS, 0, stream>>>(logits, pboxes, tlabels,
                                                      tboxes, ws, out);
    match_kernel<<<Nn, MTHREADS, 0, stream>>>(logits, pboxes, tlabels,
                                              tboxes, ws, out);
}